// Round 1
// baseline (20.339 us; speedup 1.0000x reference)
//
#include <hip/hip_runtime.h>

// SeeSawLoss: out = mean over (b,h,w) of  log(sum_i exp(l[b,i,h,w]) * M[b,i,t]) - l[b,t,h,w]
//   M[b,i,t] = (w[b,i] > w[b,t]) ? w[b,i]/w[b,t] : 1
// B=8, N=128, H=W=128.

#define B_   8
#define N_   128
#define HW_  16384            // 128*128
#define BLOCK 256
#define BLOCKS_PER_B (HW_ / BLOCK)   // 64
#define NBLOCKS (B_ * BLOCKS_PER_B)  // 512
#define NPIX (B_ * HW_)              // 131072

__global__ __launch_bounds__(BLOCK) void seesaw_main(
    const float* __restrict__ logit,
    const int*   __restrict__ target,
    const float* __restrict__ weight,
    float*       __restrict__ partials)
{
    __shared__ float w_s[N_];
    __shared__ float red[BLOCK / 64];

    const int b   = blockIdx.x / BLOCKS_PER_B;
    const int pix = (blockIdx.x % BLOCKS_PER_B) * BLOCK + threadIdx.x;

    if (threadIdx.x < N_) w_s[threadIdx.x] = weight[b * N_ + threadIdx.x];
    __syncthreads();

    const int   t      = target[b * HW_ + pix];
    const float wt     = w_s[t];
    const float inv_wt = 1.0f / wt;

    const float* lp = logit + (size_t)b * N_ * HW_ + pix;

    float acc = 0.0f;   // denom_t
    float lt  = 0.0f;   // logit at target class

    #pragma unroll 8
    for (int i = 0; i < N_; ++i) {
        const float l  = lp[(size_t)i * HW_];
        const float e  = __expf(l);
        const float wi = w_s[i];
        const float m  = (wi > wt) ? wi * inv_wt : 1.0f;
        acc = fmaf(e, m, acc);
        if (i == t) lt = l;
    }

    float loss = __logf(acc) - lt;

    // wave (64-lane) reduction
    #pragma unroll
    for (int o = 32; o > 0; o >>= 1) loss += __shfl_down(loss, o, 64);

    const int lane = threadIdx.x & 63;
    const int wid  = threadIdx.x >> 6;
    if (lane == 0) red[wid] = loss;
    __syncthreads();

    if (threadIdx.x == 0) {
        float s = 0.0f;
        #pragma unroll
        for (int k = 0; k < BLOCK / 64; ++k) s += red[k];
        partials[blockIdx.x] = s;
    }
}

__global__ __launch_bounds__(256) void seesaw_reduce(
    const float* __restrict__ partials,
    float*       __restrict__ out)
{
    __shared__ float red[4];
    float s = partials[threadIdx.x] + partials[threadIdx.x + 256];

    #pragma unroll
    for (int o = 32; o > 0; o >>= 1) s += __shfl_down(s, o, 64);

    const int lane = threadIdx.x & 63;
    const int wid  = threadIdx.x >> 6;
    if (lane == 0) red[wid] = s;
    __syncthreads();

    if (threadIdx.x == 0) {
        float tot = red[0] + red[1] + red[2] + red[3];
        out[0] = tot / (float)NPIX;
    }
}

extern "C" void kernel_launch(void* const* d_in, const int* in_sizes, int n_in,
                              void* d_out, int out_size, void* d_ws, size_t ws_size,
                              hipStream_t stream)
{
    const float* logit  = (const float*)d_in[0];
    const int*   target = (const int*)  d_in[1];
    const float* weight = (const float*)d_in[2];
    // d_in[3] = epoch (unused by the reference math)

    float* partials = (float*)d_ws;          // NBLOCKS floats
    float* out      = (float*)d_out;

    seesaw_main<<<NBLOCKS, BLOCK, 0, stream>>>(logit, target, weight, partials);
    seesaw_reduce<<<1, 256, 0, stream>>>(partials, out);
}